// Round 1
// baseline (355.186 us; speedup 1.0000x reference)
//
#include <hip/hip_runtime.h>
#include <math.h>

#define NN 50000
#define NE 800000
#define NEG_SLOPE 0.2f
#define LN_EPS 1e-5f
#define SROW 264  // LDS stage row stride in ushorts (256 + 8 pad)

typedef unsigned short ushort_t;
typedef unsigned int uint_t;
typedef __attribute__((ext_vector_type(8))) short bf16x8;
typedef __attribute__((ext_vector_type(4))) float f32x4;

__device__ __forceinline__ float bf2f(ushort_t u) {
    return __uint_as_float(((uint_t)u) << 16);
}
__device__ __forceinline__ ushort_t f2bf(float f) {
    uint_t b = __float_as_uint(f);
    uint_t r = (b + 0x7fffu + ((b >> 16) & 1u)) >> 16;
    return (ushort_t)r;
}
__device__ __forceinline__ float ldx(const void* p, size_t i, int isbf) {
    return isbf ? bf2f(((const ushort_t*)p)[i]) : ((const float*)p)[i];
}
__device__ __forceinline__ int clampN(int v) {
    return v < 0 ? 0 : (v >= NN ? NN - 1 : v);
}
__device__ __forceinline__ int ld_src(const int* ei, int e, int f64) {
    return clampN(f64 ? ei[2 * e] : ei[e]);
}
__device__ __forceinline__ int ld_dst(const int* ei, int e, int f64) {
    return clampN(f64 ? ei[2 * NE + 2 * e] : ei[NE + e]);
}
__device__ __forceinline__ int sniff_isbf(const void* hptr) {
    const ushort_t* hu = (const ushort_t*)hptr;
    int bf = 1;
    for (int i = 0; i < 512; i += 2) {
        uint_t ex = (hu[i] >> 7) & 0xFFu;
        if (ex > 0x8Cu) bf = 0;  // |v| >= ~1e4 -> not bf16 data
    }
    return bf;
}
__device__ __forceinline__ int sniff_f64(const int* ei) {
    return (ei[1] == 0 && ei[3] == 0 && ei[5] == 0 && ei[7] == 0) ? 1 : 0;
}

// Merged setup: flags + zero deg + M (block0) + W_ext + optional h->bf16.
__global__ __launch_bounds__(256) void setup(
    const void* __restrict__ lin_W, const void* __restrict__ lin_edge_W,
    const void* __restrict__ att_src, const void* __restrict__ att_dst,
    const void* __restrict__ att_edge, const void* __restrict__ h_in,
    const int* __restrict__ ei, float* __restrict__ Mbuf,
    ushort_t* __restrict__ wext, ushort_t* __restrict__ hbf,
    int* __restrict__ deg, int* __restrict__ flags) {
    int tid = threadIdx.x, lane = tid & 63;
    int nthreads = gridDim.x * 256;
    int gtid = blockIdx.x * 256 + tid;
    __shared__ int s_isbf;
    if (tid == 0) s_isbf = sniff_isbf(h_in);
    __syncthreads();
    int isbf = s_isbf;
    if (gtid == 0) {
        flags[0] = sniff_f64(ei);
        flags[1] = isbf;
    }
    for (int i = gtid; i < NN; i += nthreads) deg[i] = 0;
    if (blockIdx.x == 0) {
        for (int rep = 0; rep < 2; ++rep) {
            int idx = rep * 256 + tid;  // l=idx>>8, h=(idx>>6)&3, c=idx&63
            int l = idx >> 8, hc = idx & 255;
            float ae = ldx(att_edge, l * 256 + hc, isbf);
            size_t b3 = ((size_t)l * 256 + hc) * 3;
            float q0 = ae * ldx(lin_edge_W, b3 + 0, isbf);
            float q1 = ae * ldx(lin_edge_W, b3 + 1, isbf);
            float q2 = ae * ldx(lin_edge_W, b3 + 2, isbf);
            for (int off = 32; off > 0; off >>= 1) {
                q0 += __shfl_down(q0, off);
                q1 += __shfl_down(q1, off);
                q2 += __shfl_down(q2, off);
            }
            if (lane == 0) {
                int h = (idx >> 6) & 3;
                Mbuf[(l * 4 + h) * 3 + 0] = q0;
                Mbuf[(l * 4 + h) * 3 + 1] = q1;
                Mbuf[(l * 4 + h) * 3 + 2] = q2;
            }
        }
    }
    // W_ext[l][272][64]: rows 0..255 = lin_W; 256..259 = u_src[h];
    // 260..263 = u_dst[h]; 264..271 = 0
    for (int idx = gtid; idx < 2 * 272 * 64; idx += nthreads) {
        int d = idx & 63;
        int row = (idx >> 6) % 272;
        int l = idx / (272 * 64);
        float v = 0.f;
        if (row < 256) {
            v = ldx(lin_W, ((size_t)l * 256 + row) * 64 + d, isbf);
        } else if (row < 264) {
            int h = (row - 256) & 3;
            const void* att = (row < 260) ? att_src : att_dst;
            for (int c = 0; c < 64; ++c) {
                v += ldx(lin_W, ((size_t)l * 256 + h * 64 + c) * 64 + d, isbf) *
                     ldx(att, l * 256 + h * 64 + c, isbf);
            }
        }
        wext[((size_t)l * 272 + row) * 64 + d] = f2bf(v);
    }
    if (!isbf) {
        for (int i = gtid; i < NN * 64; i += nthreads)
            hbf[i] = f2bf(((const float*)h_in)[i]);
    }
}

// ---------------- CSR build ----------------

__global__ void csr_hist_pos(const int* __restrict__ ei, int* __restrict__ deg,
                             int* __restrict__ pos, const int* __restrict__ flags) {
    int e = blockIdx.x * 256 + threadIdx.x;
    if (e >= NE) return;
    pos[e] = atomicAdd(&deg[ld_dst(ei, e, flags[0])], 1);
}

__global__ __launch_bounds__(1024) void csr_scan1(const int* __restrict__ deg,
                                                  int* __restrict__ rowptr,
                                                  int* __restrict__ bsum) {
    __shared__ int sh[1024];
    int i = blockIdx.x * 1024 + threadIdx.x;
    int v = (i < NN) ? deg[i] : 0;
    sh[threadIdx.x] = v;
    __syncthreads();
    for (int off = 1; off < 1024; off <<= 1) {
        int t = (threadIdx.x >= off) ? sh[threadIdx.x - off] : 0;
        __syncthreads();
        sh[threadIdx.x] += t;
        __syncthreads();
    }
    if (i < NN) rowptr[i] = sh[threadIdx.x] - v;
    if (threadIdx.x == 1023) bsum[blockIdx.x] = sh[1023];
}

// merged scan2+scan3: each block wave-sums bsum[0..blockIdx) redundantly
__global__ __launch_bounds__(1024) void csr_scan23(int* __restrict__ rowptr,
                                                   const int* __restrict__ bsum,
                                                   int nb) {
    __shared__ int off_sh;
    int tid = threadIdx.x;
    if (tid < 64) {
        int v = (tid < blockIdx.x && tid < nb) ? bsum[tid] : 0;
        for (int off = 32; off > 0; off >>= 1) v += __shfl_down(v, off);
        if (tid == 0) off_sh = v;
    }
    __syncthreads();
    int i = blockIdx.x * 1024 + tid;
    if (i < NN) rowptr[i] += off_sh;
    if (i == 0) rowptr[NN] = NE;
}

__global__ void csr_fill(const int* __restrict__ ei, const void* __restrict__ edge_attr,
                         const int* __restrict__ rowptr, const int* __restrict__ pos,
                         float4* __restrict__ edata, const int* __restrict__ flags) {
    int e = blockIdx.x * 256 + threadIdx.x;
    if (e >= NE) return;
    int f64 = flags[0], isbf = flags[1];
    int s = ld_src(ei, e, f64), d = ld_dst(ei, e, f64);
    float4 ed;
    ed.x = ldx(edge_attr, (size_t)e * 3 + 0, isbf);
    ed.y = ldx(edge_attr, (size_t)e * 3 + 1, isbf);
    ed.z = ldx(edge_attr, (size_t)e * 3 + 2, isbf);
    ed.w = __int_as_float(s);
    edata[rowptr[d] + pos[e]] = ed;
}

// ---------------- per-layer kernels ----------------

// MFMA GEMM, wext fragments register-resident (r10-proven).
// xb layout is now plain wcol order: xb[node*256 + h*64 + c].
__global__ __launch_bounds__(256) void node_linear(
    const void* __restrict__ h_in, const ushort_t* __restrict__ hbf,
    const ushort_t* __restrict__ zbuf, const ushort_t* __restrict__ wext,
    ushort_t* __restrict__ xb, float* __restrict__ a_src, float* __restrict__ a_dst,
    const int* __restrict__ flags, int layer) {
    __shared__ __align__(16) ushort_t st_all[4 * 16 * SROW];  // 33792 B
    int isbf = flags[1];
    int tid = threadIdx.x, wv = tid >> 6, lane = tid & 63;
    int q = lane >> 4, mi = lane & 15;
    const ushort_t* zsrc = (layer == 0) ? (isbf ? (const ushort_t*)h_in : hbf) : zbuf;
    const ushort_t* wl = wext + (size_t)layer * 272 * 64;
    bf16x8 wf[34];
#pragma unroll
    for (int t = 0; t < 17; ++t) {
        const ushort_t* wrow = wl + (size_t)(t * 16 + mi) * 64;
        wf[2 * t]     = *(const bf16x8*)(wrow + q * 8);
        wf[2 * t + 1] = *(const bf16x8*)(wrow + 32 + q * 8);
    }
    ushort_t* st = st_all + wv * 16 * SROW;
    int gwave = blockIdx.x * 4 + wv, nwaves = gridDim.x * 4;
    for (int tile = gwave; tile < NN / 16; tile += nwaves) {
        int mbase = tile * 16, mynode = mbase + mi;
        const ushort_t* zrow = zsrc + (size_t)mynode * 64;
        bf16x8 b0 = *(const bf16x8*)(zrow + q * 8);
        bf16x8 b1 = *(const bf16x8*)(zrow + 32 + q * 8);
#pragma unroll
        for (int t = 0; t < 17; ++t) {
            f32x4 acc = {0.f, 0.f, 0.f, 0.f};
            // D col=lane&15 -> node, row=q*4+r -> wcol (verified r6/r7)
            acc = __builtin_amdgcn_mfma_f32_16x16x32_bf16(wf[2 * t], b0, acc, 0, 0, 0);
            acc = __builtin_amdgcn_mfma_f32_16x16x32_bf16(wf[2 * t + 1], b1, acc, 0, 0, 0);
            if (t < 16) {
                ushort4 pk;
                pk.x = f2bf(acc[0]);
                pk.y = f2bf(acc[1]);
                pk.z = f2bf(acc[2]);
                pk.w = f2bf(acc[3]);
                // st[node_local][wcol], wcol = t*16 + q*4 + r
                *(ushort4*)(st + mi * SROW + t * 16 + q * 4) = pk;
            } else {
                float4 av;
                av.x = acc[0]; av.y = acc[1]; av.z = acc[2]; av.w = acc[3];
                if (q == 0) *(float4*)(a_src + (size_t)mynode * 4) = av;
                else if (q == 1) *(float4*)(a_dst + (size_t)mynode * 4) = av;
            }
        }
        // write xb in wcol order: lane carries wcols lane*4..lane*4+3
        for (int nn = 0; nn < 16; ++nn) {
            int node = mbase + nn;
            ushort4 pk = *(const ushort4*)(st + nn * SROW + lane * 4);
            *(ushort4*)(xb + (size_t)node * 256 + lane * 4) = pk;
        }
    }
}

// One wave per node. Each lane owns ONE head (lane>>4) and 4 channels
// ((lane&15)*4..+3): 1 scalar weight per edge instead of 4, zero-padded
// weight quads in LDS so the hot loop has no tail conditionals.
__global__ __launch_bounds__(256) void node_aggregate(
    const int* __restrict__ rowptr, const float4* __restrict__ edata,
    const float* __restrict__ a_src, const float* __restrict__ a_dst,
    const ushort_t* __restrict__ xb, const float* __restrict__ Mbuf,
    const void* __restrict__ bias, const void* __restrict__ gamma,
    const void* __restrict__ beta, ushort_t* __restrict__ zout,
    void* __restrict__ outp, const int* __restrict__ flags, int layer, int last) {
    __shared__ __align__(16) float wq[4][16][4][4];  // [wave][quad][head][edge] 4 KB
    __shared__ __align__(16) int sq[4][16][4];       // [wave][quad][edge] byte offs 1 KB
    int isbf = flags[1];
    int wv = threadIdx.x >> 6;
    int lane = threadIdx.x & 63;
    int hidx = lane >> 4;
    int ch0 = (lane & 15) << 2;             // channel within head
    int loff = ((hidx << 6) + ch0) << 1;    // byte offset of lane's 4 channels
    int n = blockIdx.x * 4 + wv;
    float M[12];
#pragma unroll
    for (int i = 0; i < 12; ++i) M[i] = Mbuf[layer * 12 + i];
    float4 ad = *(const float4*)(a_dst + (size_t)n * 4);
    int start = rowptr[n], end = rowptr[n + 1];
    const char* xbc = (const char*)xb;
    float acc0 = 0.f, acc1 = 0.f, acc2 = 0.f, acc3 = 0.f;
    float den = 0.f;
    for (int cb = start; cb < end; cb += 64) {
        int m = end - cb;
        if (m > 64) m = 64;
        {
            int le = lane < m ? lane : 0;
            float4 ed = edata[cb + le];
            int s = __float_as_int(ed.w);
            float4 as4 = *(const float4*)(a_src + (size_t)s * 4);
            float t0 = as4.x + ad.x + ed.x * M[0] + ed.y * M[1] + ed.z * M[2];
            float t1 = as4.y + ad.y + ed.x * M[3] + ed.y * M[4] + ed.z * M[5];
            float t2 = as4.z + ad.z + ed.x * M[6] + ed.y * M[7] + ed.z * M[8];
            float t3 = as4.w + ad.w + ed.x * M[9] + ed.y * M[10] + ed.z * M[11];
            t0 = t0 > 0.f ? t0 : NEG_SLOPE * t0;
            t1 = t1 > 0.f ? t1 : NEG_SLOPE * t1;
            t2 = t2 > 0.f ? t2 : NEG_SLOPE * t2;
            t3 = t3 > 0.f ? t3 : NEG_SLOPE * t3;
            float e0 = __expf(fminf(t0, 80.f));
            float e1 = __expf(fminf(t1, 80.f));
            float e2 = __expf(fminf(t2, 80.f));
            float e3 = __expf(fminf(t3, 80.f));
            if (lane >= m) { e0 = 0.f; e1 = 0.f; e2 = 0.f; e3 = 0.f; s = 0; }
            int jq = lane >> 2, r = lane & 3;
            sq[wv][jq][r] = s << 9;  // pre-shifted row byte offset (512 B/row)
            wq[wv][jq][0][r] = e0;
            wq[wv][jq][1][r] = e1;
            wq[wv][jq][2][r] = e2;
            wq[wv][jq][3][r] = e3;
        }
        int mq = (m + 3) >> 2;
        for (int j = 0; j < mq; ++j) {
            float4 w4 = *(const float4*)&wq[wv][j][hidx][0];
            int4 s4 = *(const int4*)&sq[wv][j][0];
            ushort4 x0 = *(const ushort4*)(xbc + (size_t)(unsigned)(s4.x + loff));
            ushort4 x1 = *(const ushort4*)(xbc + (size_t)(unsigned)(s4.y + loff));
            ushort4 x2 = *(const ushort4*)(xbc + (size_t)(unsigned)(s4.z + loff));
            ushort4 x3 = *(const ushort4*)(xbc + (size_t)(unsigned)(s4.w + loff));
            acc0 = fmaf(w4.x, bf2f(x0.x), acc0);
            acc1 = fmaf(w4.x, bf2f(x0.y), acc1);
            acc2 = fmaf(w4.x, bf2f(x0.z), acc2);
            acc3 = fmaf(w4.x, bf2f(x0.w), acc3);
            acc0 = fmaf(w4.y, bf2f(x1.x), acc0);
            acc1 = fmaf(w4.y, bf2f(x1.y), acc1);
            acc2 = fmaf(w4.y, bf2f(x1.z), acc2);
            acc3 = fmaf(w4.y, bf2f(x1.w), acc3);
            acc0 = fmaf(w4.z, bf2f(x2.x), acc0);
            acc1 = fmaf(w4.z, bf2f(x2.y), acc1);
            acc2 = fmaf(w4.z, bf2f(x2.z), acc2);
            acc3 = fmaf(w4.z, bf2f(x2.w), acc3);
            acc0 = fmaf(w4.w, bf2f(x3.x), acc0);
            acc1 = fmaf(w4.w, bf2f(x3.y), acc1);
            acc2 = fmaf(w4.w, bf2f(x3.z), acc2);
            acc3 = fmaf(w4.w, bf2f(x3.w), acc3);
            den += (w4.x + w4.y) + (w4.z + w4.w);
        }
    }
    // per-head normalize, then mean over heads (lanes l, l^16, l^32, l^48)
    float inv = 1.f / (den + 1e-16f);
    float v0 = acc0 * inv, v1 = acc1 * inv, v2 = acc2 * inv, v3 = acc3 * inv;
    v0 += __shfl_xor(v0, 16); v0 += __shfl_xor(v0, 32);
    v1 += __shfl_xor(v1, 16); v1 += __shfl_xor(v1, 32);
    v2 += __shfl_xor(v2, 16); v2 += __shfl_xor(v2, 32);
    v3 += __shfl_xor(v3, 16); v3 += __shfl_xor(v3, 32);
    size_t pb = (size_t)layer * 64 + ch0;
    v0 = ldx(bias, pb + 0, isbf) + 0.25f * v0;
    v1 = ldx(bias, pb + 1, isbf) + 0.25f * v1;
    v2 = ldx(bias, pb + 2, isbf) + 0.25f * v2;
    v3 = ldx(bias, pb + 3, isbf) + 0.25f * v3;
    // LayerNorm over the 64 channels held by each 16-lane group
    float lsum = (v0 + v1) + (v2 + v3);
    lsum += __shfl_xor(lsum, 1);
    lsum += __shfl_xor(lsum, 2);
    lsum += __shfl_xor(lsum, 4);
    lsum += __shfl_xor(lsum, 8);
    float mu = lsum * (1.f / 64.f);
    float d0 = v0 - mu, d1 = v1 - mu, d2 = v2 - mu, d3 = v3 - mu;
    float ss = (d0 * d0 + d1 * d1) + (d2 * d2 + d3 * d3);
    ss += __shfl_xor(ss, 1);
    ss += __shfl_xor(ss, 2);
    ss += __shfl_xor(ss, 4);
    ss += __shfl_xor(ss, 8);
    float rstd = rsqrtf(ss * (1.f / 64.f) + LN_EPS);
    float l0 = d0 * rstd * ldx(gamma, pb + 0, isbf) + ldx(beta, pb + 0, isbf);
    float l1 = d1 * rstd * ldx(gamma, pb + 1, isbf) + ldx(beta, pb + 1, isbf);
    float l2 = d2 * rstd * ldx(gamma, pb + 2, isbf) + ldx(beta, pb + 2, isbf);
    float l3 = d3 * rstd * ldx(gamma, pb + 3, isbf) + ldx(beta, pb + 3, isbf);
    float s0 = l0 / (1.f + __expf(-l0));
    float s1 = l1 / (1.f + __expf(-l1));
    float s2 = l2 / (1.f + __expf(-l2));
    float s3 = l3 / (1.f + __expf(-l3));
    if (hidx == 0) {  // groups are replicas; only group 0 stores
        size_t base = (size_t)n * 64 + ch0;
        if (last) {
            if (isbf) {
                ushort4 pk;
                pk.x = f2bf(s0); pk.y = f2bf(s1); pk.z = f2bf(s2); pk.w = f2bf(s3);
                *(ushort4*)((ushort_t*)outp + base) = pk;
            } else {
                float4 fv;
                fv.x = s0; fv.y = s1; fv.z = s2; fv.w = s3;
                *(float4*)((float*)outp + base) = fv;
            }
        } else {
            ushort4 pk;
            pk.x = f2bf(s0); pk.y = f2bf(s1); pk.z = f2bf(s2); pk.w = f2bf(s3);
            *(ushort4*)(zout + base) = pk;
        }
    }
}

extern "C" void kernel_launch(void* const* d_in, const int* in_sizes, int n_in,
                              void* d_out, int out_size, void* d_ws, size_t ws_size,
                              hipStream_t stream) {
    int off = (in_sizes[0] == 1) ? 1 : 0;
    const void* h_in  = d_in[off + 0];
    const int*  ei    = (const int*)d_in[off + 1];
    const void* eattr = d_in[off + 2];
    const void* linW  = d_in[off + 3];
    const void* linEW = d_in[off + 4];
    const void* attS  = d_in[off + 5];
    const void* attD  = d_in[off + 6];
    const void* attE  = d_in[off + 7];
    const void* bias  = d_in[off + 8];
    const void* gamma = d_in[off + 9];
    const void* beta  = d_in[off + 10];

    // bump allocator, 256 B aligned (~56.5 MB)
    char* w = (char*)d_ws;
    size_t o = 0;
    auto alloc = [&](size_t bytes) {
        void* q = w + o;
        o += (bytes + 255) & ~(size_t)255;
        return q;
    };
    int*    flags  = (int*)alloc(8);
    float*  Mbuf   = (float*)alloc(24 * 4);
    ushort_t* wext = (ushort_t*)alloc((size_t)2 * 272 * 64 * 2);
    float*  a_src  = (float*)alloc((size_t)NN * 4 * 4);
    float*  a_dst  = (float*)alloc((size_t)NN * 4 * 4);
    int*    rowptr = (int*)alloc((size_t)(NN + 1) * 4);
    int*    deg    = (int*)alloc((size_t)NN * 4);
    int*    pos    = (int*)alloc((size_t)NE * 4);
    int*    bsum   = (int*)alloc(256 * 4);
    ushort_t* zbuf = (ushort_t*)alloc((size_t)NN * 64 * 2);
    ushort_t* hbf  = (ushort_t*)alloc((size_t)NN * 64 * 2);
    ushort_t* xb   = (ushort_t*)alloc((size_t)NN * 256 * 2);
    float4* edata  = (float4*)alloc((size_t)NE * 16);

    int nb = (NN + 1023) / 1024;  // 49
    setup<<<256, 256, 0, stream>>>(linW, linEW, attS, attD, attE, h_in, ei,
                                   Mbuf, wext, hbf, deg, flags);
    csr_hist_pos<<<(NE + 255) / 256, 256, 0, stream>>>(ei, deg, pos, flags);
    csr_scan1<<<nb, 1024, 0, stream>>>(deg, rowptr, bsum);
    csr_scan23<<<nb, 1024, 0, stream>>>(rowptr, bsum, nb);
    csr_fill<<<(NE + 255) / 256, 256, 0, stream>>>(ei, eattr, rowptr, pos, edata, flags);

    for (int l = 0; l < 2; ++l) {
        node_linear<<<512, 256, 0, stream>>>(h_in, hbf, zbuf, wext, xb,
                                             a_src, a_dst, flags, l);
        node_aggregate<<<NN / 4, 256, 0, stream>>>(rowptr, edata, a_src, a_dst,
                                                   xb, Mbuf, bias, gamma, beta,
                                                   zbuf, d_out, flags, l, l == 1);
    }
}

// Round 2
// 339.908 us; speedup vs baseline: 1.0449x; 1.0449x over previous
//
#include <hip/hip_runtime.h>
#include <math.h>

#define NN 50000
#define NE 800000
#define NEG_SLOPE 0.2f
#define LN_EPS 1e-5f
#define SROW 264  // LDS stage row stride in ushorts (256 + 8 pad)

typedef unsigned short ushort_t;
typedef unsigned int uint_t;
typedef __attribute__((ext_vector_type(8))) short bf16x8;
typedef __attribute__((ext_vector_type(4))) float f32x4;

__device__ __forceinline__ float bf2f(ushort_t u) {
    return __uint_as_float(((uint_t)u) << 16);
}
__device__ __forceinline__ ushort_t f2bf(float f) {
    uint_t b = __float_as_uint(f);
    uint_t r = (b + 0x7fffu + ((b >> 16) & 1u)) >> 16;
    return (ushort_t)r;
}
__device__ __forceinline__ float ldx(const void* p, size_t i, int isbf) {
    return isbf ? bf2f(((const ushort_t*)p)[i]) : ((const float*)p)[i];
}
__device__ __forceinline__ int clampN(int v) {
    return v < 0 ? 0 : (v >= NN ? NN - 1 : v);
}
__device__ __forceinline__ int ld_src(const int* ei, int e, int f64) {
    return clampN(f64 ? ei[2 * e] : ei[e]);
}
__device__ __forceinline__ int ld_dst(const int* ei, int e, int f64) {
    return clampN(f64 ? ei[2 * NE + 2 * e] : ei[NE + e]);
}
__device__ __forceinline__ int sniff_isbf(const void* hptr) {
    const ushort_t* hu = (const ushort_t*)hptr;
    int bf = 1;
    for (int i = 0; i < 512; i += 2) {
        uint_t ex = (hu[i] >> 7) & 0xFFu;
        if (ex > 0x8Cu) bf = 0;  // |v| >= ~1e4 -> not bf16 data
    }
    return bf;
}
__device__ __forceinline__ int sniff_f64(const int* ei) {
    return (ei[1] == 0 && ei[3] == 0 && ei[5] == 0 && ei[7] == 0) ? 1 : 0;
}

// Merged setup: flags + zero deg + M (block0) + W_ext + optional h->bf16.
__global__ __launch_bounds__(256) void setup(
    const void* __restrict__ lin_W, const void* __restrict__ lin_edge_W,
    const void* __restrict__ att_src, const void* __restrict__ att_dst,
    const void* __restrict__ att_edge, const void* __restrict__ h_in,
    const int* __restrict__ ei, float* __restrict__ Mbuf,
    ushort_t* __restrict__ wext, ushort_t* __restrict__ hbf,
    int* __restrict__ deg, int* __restrict__ flags) {
    int tid = threadIdx.x, lane = tid & 63;
    int nthreads = gridDim.x * 256;
    int gtid = blockIdx.x * 256 + tid;
    __shared__ int s_isbf;
    if (tid == 0) s_isbf = sniff_isbf(h_in);
    __syncthreads();
    int isbf = s_isbf;
    if (gtid == 0) {
        flags[0] = sniff_f64(ei);
        flags[1] = isbf;
    }
    for (int i = gtid; i < NN; i += nthreads) deg[i] = 0;
    if (blockIdx.x == 0) {
        for (int rep = 0; rep < 2; ++rep) {
            int idx = rep * 256 + tid;  // l=idx>>8, h=(idx>>6)&3, c=idx&63
            int l = idx >> 8, hc = idx & 255;
            float ae = ldx(att_edge, l * 256 + hc, isbf);
            size_t b3 = ((size_t)l * 256 + hc) * 3;
            float q0 = ae * ldx(lin_edge_W, b3 + 0, isbf);
            float q1 = ae * ldx(lin_edge_W, b3 + 1, isbf);
            float q2 = ae * ldx(lin_edge_W, b3 + 2, isbf);
            for (int off = 32; off > 0; off >>= 1) {
                q0 += __shfl_down(q0, off);
                q1 += __shfl_down(q1, off);
                q2 += __shfl_down(q2, off);
            }
            if (lane == 0) {
                int h = (idx >> 6) & 3;
                Mbuf[(l * 4 + h) * 3 + 0] = q0;
                Mbuf[(l * 4 + h) * 3 + 1] = q1;
                Mbuf[(l * 4 + h) * 3 + 2] = q2;
            }
        }
    }
    // W_ext[l][272][64]: rows 0..255 = lin_W; 256..259 = u_src[h];
    // 260..263 = u_dst[h]; 264..271 = 0
    for (int idx = gtid; idx < 2 * 272 * 64; idx += nthreads) {
        int d = idx & 63;
        int row = (idx >> 6) % 272;
        int l = idx / (272 * 64);
        float v = 0.f;
        if (row < 256) {
            v = ldx(lin_W, ((size_t)l * 256 + row) * 64 + d, isbf);
        } else if (row < 264) {
            int h = (row - 256) & 3;
            const void* att = (row < 260) ? att_src : att_dst;
            for (int c = 0; c < 64; ++c) {
                v += ldx(lin_W, ((size_t)l * 256 + h * 64 + c) * 64 + d, isbf) *
                     ldx(att, l * 256 + h * 64 + c, isbf);
            }
        }
        wext[((size_t)l * 272 + row) * 64 + d] = f2bf(v);
    }
    if (!isbf) {
        for (int i = gtid; i < NN * 64; i += nthreads)
            hbf[i] = f2bf(((const float*)h_in)[i]);
    }
}

// ---------------- CSR build ----------------

__global__ void csr_hist_pos(const int* __restrict__ ei, int* __restrict__ deg,
                             int* __restrict__ pos, const int* __restrict__ flags) {
    int e = blockIdx.x * 256 + threadIdx.x;
    if (e >= NE) return;
    pos[e] = atomicAdd(&deg[ld_dst(ei, e, flags[0])], 1);
}

__global__ __launch_bounds__(1024) void csr_scan1(const int* __restrict__ deg,
                                                  int* __restrict__ rowptr,
                                                  int* __restrict__ bsum) {
    __shared__ int sh[1024];
    int i = blockIdx.x * 1024 + threadIdx.x;
    int v = (i < NN) ? deg[i] : 0;
    sh[threadIdx.x] = v;
    __syncthreads();
    for (int off = 1; off < 1024; off <<= 1) {
        int t = (threadIdx.x >= off) ? sh[threadIdx.x - off] : 0;
        __syncthreads();
        sh[threadIdx.x] += t;
        __syncthreads();
    }
    if (i < NN) rowptr[i] = sh[threadIdx.x] - v;
    if (threadIdx.x == 1023) bsum[blockIdx.x] = sh[1023];
}

// merged scan2+scan3: each block wave-sums bsum[0..blockIdx) redundantly
__global__ __launch_bounds__(1024) void csr_scan23(int* __restrict__ rowptr,
                                                   const int* __restrict__ bsum,
                                                   int nb) {
    __shared__ int off_sh;
    int tid = threadIdx.x;
    if (tid < 64) {
        int v = (tid < blockIdx.x && tid < nb) ? bsum[tid] : 0;
        for (int off = 32; off > 0; off >>= 1) v += __shfl_down(v, off);
        if (tid == 0) off_sh = v;
    }
    __syncthreads();
    int i = blockIdx.x * 1024 + tid;
    if (i < NN) rowptr[i] += off_sh;
    if (i == 0) rowptr[NN] = NE;
}

__global__ void csr_fill(const int* __restrict__ ei, const void* __restrict__ edge_attr,
                         const int* __restrict__ rowptr, const int* __restrict__ pos,
                         float4* __restrict__ edata, const int* __restrict__ flags) {
    int e = blockIdx.x * 256 + threadIdx.x;
    if (e >= NE) return;
    int f64 = flags[0], isbf = flags[1];
    int s = ld_src(ei, e, f64), d = ld_dst(ei, e, f64);
    float4 ed;
    ed.x = ldx(edge_attr, (size_t)e * 3 + 0, isbf);
    ed.y = ldx(edge_attr, (size_t)e * 3 + 1, isbf);
    ed.z = ldx(edge_attr, (size_t)e * 3 + 2, isbf);
    ed.w = __int_as_float(s);
    edata[rowptr[d] + pos[e]] = ed;
}

// ---------------- per-layer kernels ----------------

// MFMA GEMM, wext fragments register-resident (r10-proven).
// xb layout (round-0): xb[node*256 + k*... ] channel-major: lane*4+k holds
// wcol k*64+lane, i.e. head k, channel lane.
__global__ __launch_bounds__(256) void node_linear(
    const void* __restrict__ h_in, const ushort_t* __restrict__ hbf,
    const ushort_t* __restrict__ zbuf, const ushort_t* __restrict__ wext,
    ushort_t* __restrict__ xb, float* __restrict__ a_src, float* __restrict__ a_dst,
    const int* __restrict__ flags, int layer) {
    __shared__ __align__(16) ushort_t st_all[4 * 16 * SROW];  // 33792 B
    int isbf = flags[1];
    int tid = threadIdx.x, wv = tid >> 6, lane = tid & 63;
    int q = lane >> 4, mi = lane & 15;
    const ushort_t* zsrc = (layer == 0) ? (isbf ? (const ushort_t*)h_in : hbf) : zbuf;
    const ushort_t* wl = wext + (size_t)layer * 272 * 64;
    bf16x8 wf[34];
#pragma unroll
    for (int t = 0; t < 17; ++t) {
        const ushort_t* wrow = wl + (size_t)(t * 16 + mi) * 64;
        wf[2 * t]     = *(const bf16x8*)(wrow + q * 8);
        wf[2 * t + 1] = *(const bf16x8*)(wrow + 32 + q * 8);
    }
    ushort_t* st = st_all + wv * 16 * SROW;
    int gwave = blockIdx.x * 4 + wv, nwaves = gridDim.x * 4;
    for (int tile = gwave; tile < NN / 16; tile += nwaves) {
        int mbase = tile * 16, mynode = mbase + mi;
        const ushort_t* zrow = zsrc + (size_t)mynode * 64;
        bf16x8 b0 = *(const bf16x8*)(zrow + q * 8);
        bf16x8 b1 = *(const bf16x8*)(zrow + 32 + q * 8);
#pragma unroll
        for (int t = 0; t < 17; ++t) {
            f32x4 acc = {0.f, 0.f, 0.f, 0.f};
            // D col=lane&15 -> node, row=q*4+r -> wcol (verified r6/r7)
            acc = __builtin_amdgcn_mfma_f32_16x16x32_bf16(wf[2 * t], b0, acc, 0, 0, 0);
            acc = __builtin_amdgcn_mfma_f32_16x16x32_bf16(wf[2 * t + 1], b1, acc, 0, 0, 0);
            if (t < 16) {
                ushort4 pk;
                pk.x = f2bf(acc[0]);
                pk.y = f2bf(acc[1]);
                pk.z = f2bf(acc[2]);
                pk.w = f2bf(acc[3]);
                *(ushort4*)(st + mi * SROW + t * 16 + q * 4) = pk;
            } else {
                float4 av;
                av.x = acc[0]; av.y = acc[1]; av.z = acc[2]; av.w = acc[3];
                if (q == 0) *(float4*)(a_src + (size_t)mynode * 4) = av;
                else if (q == 1) *(float4*)(a_dst + (size_t)mynode * 4) = av;
            }
        }
        for (int nn = 0; nn < 16; ++nn) {
            int node = mbase + nn;
            ushort4 pk;
            pk.x = st[nn * SROW + lane];
            pk.y = st[nn * SROW + 64 + lane];
            pk.z = st[nn * SROW + 128 + lane];
            pk.w = st[nn * SROW + 192 + lane];
            *(ushort4*)(xb + (size_t)node * 256 + lane * 4) = pk;
        }
    }
}

// One wave per node (round-0 structure: lane owns one channel, all 4 heads;
// 4-deep pipelined gather). New vs round-0: LDS edge buffers zero-padded so
// the hot loop has NO tail conditionals, and per-head denominators are
// computed once per 64-edge chunk via wave shfl-reduction instead of
// 16 adds per 4 edges.
__global__ __launch_bounds__(256) void node_aggregate(
    const int* __restrict__ rowptr, const float4* __restrict__ edata,
    const float* __restrict__ a_src, const float* __restrict__ a_dst,
    const ushort_t* __restrict__ xb, const float* __restrict__ Mbuf,
    const void* __restrict__ bias, const void* __restrict__ gamma,
    const void* __restrict__ beta, ushort_t* __restrict__ zout,
    void* __restrict__ outp, const int* __restrict__ flags, int layer, int last) {
    __shared__ float4 wsh[4][64];
    __shared__ int ssh[4][64];
    int isbf = flags[1];
    int wv = threadIdx.x >> 6;
    int lane = threadIdx.x & 63;
    int n = blockIdx.x * 4 + wv;
    float M[12];
#pragma unroll
    for (int i = 0; i < 12; ++i) M[i] = Mbuf[layer * 12 + i];
    float4 ad = *(const float4*)(a_dst + (size_t)n * 4);
    int start = rowptr[n], end = rowptr[n + 1];
    float acc0 = 0.f, acc1 = 0.f, acc2 = 0.f, acc3 = 0.f;
    float den0 = 0.f, den1 = 0.f, den2 = 0.f, den3 = 0.f;
    for (int cb = start; cb < end; cb += 64) {
        int m = end - cb;
        if (m > 64) m = 64;
        float4 ex = make_float4(0.f, 0.f, 0.f, 0.f);
        int s = 0;
        if (lane < m) {
            float4 ed = edata[cb + lane];
            s = __float_as_int(ed.w);
            float4 as4 = *(const float4*)(a_src + (size_t)s * 4);
            float t0 = as4.x + ad.x + ed.x * M[0] + ed.y * M[1] + ed.z * M[2];
            float t1 = as4.y + ad.y + ed.x * M[3] + ed.y * M[4] + ed.z * M[5];
            float t2 = as4.z + ad.z + ed.x * M[6] + ed.y * M[7] + ed.z * M[8];
            float t3 = as4.w + ad.w + ed.x * M[9] + ed.y * M[10] + ed.z * M[11];
            t0 = t0 > 0.f ? t0 : NEG_SLOPE * t0;
            t1 = t1 > 0.f ? t1 : NEG_SLOPE * t1;
            t2 = t2 > 0.f ? t2 : NEG_SLOPE * t2;
            t3 = t3 > 0.f ? t3 : NEG_SLOPE * t3;
            ex.x = __expf(fminf(t0, 80.f));
            ex.y = __expf(fminf(t1, 80.f));
            ex.z = __expf(fminf(t2, 80.f));
            ex.w = __expf(fminf(t3, 80.f));
        }
        wsh[wv][lane] = ex;   // lanes >= m write zeros: loop below needs no tail
        ssh[wv][lane] = s;    // padded slots gather (cached) row 0 with w=0
        // per-head denominators: one wave-reduction per 64-edge chunk
        float r0 = ex.x, r1 = ex.y, r2 = ex.z, r3 = ex.w;
        for (int off = 1; off < 64; off <<= 1) {
            r0 += __shfl_xor(r0, off);
            r1 += __shfl_xor(r1, off);
            r2 += __shfl_xor(r2, off);
            r3 += __shfl_xor(r3, off);
        }
        den0 += r0; den1 += r1; den2 += r2; den3 += r3;
        int m4 = (m + 3) & ~3;
        for (int j = 0; j < m4; j += 4) {
            int s0 = ssh[wv][j],     s1 = ssh[wv][j + 1];
            int s2 = ssh[wv][j + 2], s3 = ssh[wv][j + 3];
            float4 w0 = wsh[wv][j];
            float4 w1 = wsh[wv][j + 1];
            float4 w2 = wsh[wv][j + 2];
            float4 w3 = wsh[wv][j + 3];
            ushort4 x0 = *(const ushort4*)(xb + (size_t)s0 * 256 + lane * 4);
            ushort4 x1 = *(const ushort4*)(xb + (size_t)s1 * 256 + lane * 4);
            ushort4 x2 = *(const ushort4*)(xb + (size_t)s2 * 256 + lane * 4);
            ushort4 x3 = *(const ushort4*)(xb + (size_t)s3 * 256 + lane * 4);
            acc0 += w0.x * bf2f(x0.x) + w1.x * bf2f(x1.x) +
                    w2.x * bf2f(x2.x) + w3.x * bf2f(x3.x);
            acc1 += w0.y * bf2f(x0.y) + w1.y * bf2f(x1.y) +
                    w2.y * bf2f(x2.y) + w3.y * bf2f(x3.y);
            acc2 += w0.z * bf2f(x0.z) + w1.z * bf2f(x1.z) +
                    w2.z * bf2f(x2.z) + w3.z * bf2f(x3.z);
            acc3 += w0.w * bf2f(x0.w) + w1.w * bf2f(x1.w) +
                    w2.w * bf2f(x2.w) + w3.w * bf2f(x3.w);
        }
    }
    float v = ldx(bias, layer * 64 + lane, isbf) +
              0.25f * (acc0 / (den0 + 1e-16f) + acc1 / (den1 + 1e-16f) +
                       acc2 / (den2 + 1e-16f) + acc3 / (den3 + 1e-16f));
    float sum = v;
    for (int off = 1; off < 64; off <<= 1) sum += __shfl_xor(sum, off);
    float mu = sum * (1.f / 64.f);
    float d = v - mu;
    float vv = d * d;
    for (int off = 1; off < 64; off <<= 1) vv += __shfl_xor(vv, off);
    float var = vv * (1.f / 64.f);
    float ln = d * rsqrtf(var + LN_EPS) * ldx(gamma, layer * 64 + lane, isbf) +
               ldx(beta, layer * 64 + lane, isbf);
    float sl = ln / (1.f + __expf(-ln));
    size_t idx = (size_t)n * 64 + lane;
    if (last) {
        if (isbf) ((ushort_t*)outp)[idx] = f2bf(sl);
        else      ((float*)outp)[idx] = sl;
    } else {
        zout[idx] = f2bf(sl);
    }
}

extern "C" void kernel_launch(void* const* d_in, const int* in_sizes, int n_in,
                              void* d_out, int out_size, void* d_ws, size_t ws_size,
                              hipStream_t stream) {
    int off = (in_sizes[0] == 1) ? 1 : 0;
    const void* h_in  = d_in[off + 0];
    const int*  ei    = (const int*)d_in[off + 1];
    const void* eattr = d_in[off + 2];
    const void* linW  = d_in[off + 3];
    const void* linEW = d_in[off + 4];
    const void* attS  = d_in[off + 5];
    const void* attD  = d_in[off + 6];
    const void* attE  = d_in[off + 7];
    const void* bias  = d_in[off + 8];
    const void* gamma = d_in[off + 9];
    const void* beta  = d_in[off + 10];

    // bump allocator, 256 B aligned (~56.5 MB)
    char* w = (char*)d_ws;
    size_t o = 0;
    auto alloc = [&](size_t bytes) {
        void* q = w + o;
        o += (bytes + 255) & ~(size_t)255;
        return q;
    };
    int*    flags  = (int*)alloc(8);
    float*  Mbuf   = (float*)alloc(24 * 4);
    ushort_t* wext = (ushort_t*)alloc((size_t)2 * 272 * 64 * 2);
    float*  a_src  = (float*)alloc((size_t)NN * 4 * 4);
    float*  a_dst  = (float*)alloc((size_t)NN * 4 * 4);
    int*    rowptr = (int*)alloc((size_t)(NN + 1) * 4);
    int*    deg    = (int*)alloc((size_t)NN * 4);
    int*    pos    = (int*)alloc((size_t)NE * 4);
    int*    bsum   = (int*)alloc(256 * 4);
    ushort_t* zbuf = (ushort_t*)alloc((size_t)NN * 64 * 2);
    ushort_t* hbf  = (ushort_t*)alloc((size_t)NN * 64 * 2);
    ushort_t* xb   = (ushort_t*)alloc((size_t)NN * 256 * 2);
    float4* edata  = (float4*)alloc((size_t)NE * 16);

    int nb = (NN + 1023) / 1024;  // 49
    setup<<<256, 256, 0, stream>>>(linW, linEW, attS, attD, attE, h_in, ei,
                                   Mbuf, wext, hbf, deg, flags);
    csr_hist_pos<<<(NE + 255) / 256, 256, 0, stream>>>(ei, deg, pos, flags);
    csr_scan1<<<nb, 1024, 0, stream>>>(deg, rowptr, bsum);
    csr_scan23<<<nb, 1024, 0, stream>>>(rowptr, bsum, nb);
    csr_fill<<<(NE + 255) / 256, 256, 0, stream>>>(ei, eattr, rowptr, pos, edata, flags);

    for (int l = 0; l < 2; ++l) {
        node_linear<<<512, 256, 0, stream>>>(h_in, hbf, zbuf, wext, xb,
                                             a_src, a_dst, flags, l);
        node_aggregate<<<NN / 4, 256, 0, stream>>>(rowptr, edata, a_src, a_dst,
                                                   xb, Mbuf, bias, gamma, beta,
                                                   zbuf, d_out, flags, l, l == 1);
    }
}

// Round 3
// 336.377 us; speedup vs baseline: 1.0559x; 1.0105x over previous
//
#include <hip/hip_runtime.h>
#include <math.h>

#define NN 50000
#define NE 800000
#define NEG_SLOPE 0.2f
#define LN_EPS 1e-5f
#define SROW 264  // LDS stage row stride in ushorts (256 + 8 pad)

typedef unsigned short ushort_t;
typedef unsigned int uint_t;
typedef __attribute__((ext_vector_type(8))) short bf16x8;
typedef __attribute__((ext_vector_type(4))) float f32x4;

__device__ __forceinline__ float bf2f(ushort_t u) {
    return __uint_as_float(((uint_t)u) << 16);
}
__device__ __forceinline__ ushort_t f2bf(float f) {
    uint_t b = __float_as_uint(f);
    uint_t r = (b + 0x7fffu + ((b >> 16) & 1u)) >> 16;
    return (ushort_t)r;
}
__device__ __forceinline__ float ldx(const void* p, size_t i, int isbf) {
    return isbf ? bf2f(((const ushort_t*)p)[i]) : ((const float*)p)[i];
}
__device__ __forceinline__ int clampN(int v) {
    return v < 0 ? 0 : (v >= NN ? NN - 1 : v);
}
__device__ __forceinline__ int ld_src(const int* ei, int e, int f64) {
    return clampN(f64 ? ei[2 * e] : ei[e]);
}
__device__ __forceinline__ int ld_dst(const int* ei, int e, int f64) {
    return clampN(f64 ? ei[2 * NE + 2 * e] : ei[NE + e]);
}
__device__ __forceinline__ int sniff_isbf(const void* hptr) {
    const ushort_t* hu = (const ushort_t*)hptr;
    int bf = 1;
    for (int i = 0; i < 512; i += 2) {
        uint_t ex = (hu[i] >> 7) & 0xFFu;
        if (ex > 0x8Cu) bf = 0;  // |v| >= ~1e4 -> not bf16 data
    }
    return bf;
}
__device__ __forceinline__ int sniff_f64(const int* ei) {
    return (ei[1] == 0 && ei[3] == 0 && ei[5] == 0 && ei[7] == 0) ? 1 : 0;
}

// Merged setup: flags + zero deg + M (block0) + W_ext + optional h->bf16.
__global__ __launch_bounds__(256) void setup(
    const void* __restrict__ lin_W, const void* __restrict__ lin_edge_W,
    const void* __restrict__ att_src, const void* __restrict__ att_dst,
    const void* __restrict__ att_edge, const void* __restrict__ h_in,
    const int* __restrict__ ei, float* __restrict__ Mbuf,
    ushort_t* __restrict__ wext, ushort_t* __restrict__ hbf,
    int* __restrict__ deg, int* __restrict__ flags) {
    int tid = threadIdx.x, lane = tid & 63;
    int nthreads = gridDim.x * 256;
    int gtid = blockIdx.x * 256 + tid;
    __shared__ int s_isbf;
    if (tid == 0) s_isbf = sniff_isbf(h_in);
    __syncthreads();
    int isbf = s_isbf;
    if (gtid == 0) {
        flags[0] = sniff_f64(ei);
        flags[1] = isbf;
    }
    for (int i = gtid; i < NN; i += nthreads) deg[i] = 0;
    if (blockIdx.x == 0) {
        for (int rep = 0; rep < 2; ++rep) {
            int idx = rep * 256 + tid;  // l=idx>>8, h=(idx>>6)&3, c=idx&63
            int l = idx >> 8, hc = idx & 255;
            float ae = ldx(att_edge, l * 256 + hc, isbf);
            size_t b3 = ((size_t)l * 256 + hc) * 3;
            float q0 = ae * ldx(lin_edge_W, b3 + 0, isbf);
            float q1 = ae * ldx(lin_edge_W, b3 + 1, isbf);
            float q2 = ae * ldx(lin_edge_W, b3 + 2, isbf);
            for (int off = 32; off > 0; off >>= 1) {
                q0 += __shfl_down(q0, off);
                q1 += __shfl_down(q1, off);
                q2 += __shfl_down(q2, off);
            }
            if (lane == 0) {
                int h = (idx >> 6) & 3;
                Mbuf[(l * 4 + h) * 3 + 0] = q0;
                Mbuf[(l * 4 + h) * 3 + 1] = q1;
                Mbuf[(l * 4 + h) * 3 + 2] = q2;
            }
        }
    }
    // W_ext[l][272][64]: rows 0..255 = lin_W; 256..259 = u_src[h];
    // 260..263 = u_dst[h]; 264..271 = 0
    for (int idx = gtid; idx < 2 * 272 * 64; idx += nthreads) {
        int d = idx & 63;
        int row = (idx >> 6) % 272;
        int l = idx / (272 * 64);
        float v = 0.f;
        if (row < 256) {
            v = ldx(lin_W, ((size_t)l * 256 + row) * 64 + d, isbf);
        } else if (row < 264) {
            int h = (row - 256) & 3;
            const void* att = (row < 260) ? att_src : att_dst;
            for (int c = 0; c < 64; ++c) {
                v += ldx(lin_W, ((size_t)l * 256 + h * 64 + c) * 64 + d, isbf) *
                     ldx(att, l * 256 + h * 64 + c, isbf);
            }
        }
        wext[((size_t)l * 272 + row) * 64 + d] = f2bf(v);
    }
    if (!isbf) {
        for (int i = gtid; i < NN * 64; i += nthreads)
            hbf[i] = f2bf(((const float*)h_in)[i]);
    }
}

// ---------------- CSR build ----------------

__global__ void csr_hist_pos(const int* __restrict__ ei, int* __restrict__ deg,
                             int* __restrict__ pos, const int* __restrict__ flags) {
    int e = blockIdx.x * 256 + threadIdx.x;
    if (e >= NE) return;
    pos[e] = atomicAdd(&deg[ld_dst(ei, e, flags[0])], 1);
}

__global__ __launch_bounds__(1024) void csr_scan1(const int* __restrict__ deg,
                                                  int* __restrict__ rowptr,
                                                  int* __restrict__ bsum) {
    __shared__ int sh[1024];
    int i = blockIdx.x * 1024 + threadIdx.x;
    int v = (i < NN) ? deg[i] : 0;
    sh[threadIdx.x] = v;
    __syncthreads();
    for (int off = 1; off < 1024; off <<= 1) {
        int t = (threadIdx.x >= off) ? sh[threadIdx.x - off] : 0;
        __syncthreads();
        sh[threadIdx.x] += t;
        __syncthreads();
    }
    if (i < NN) rowptr[i] = sh[threadIdx.x] - v;
    if (threadIdx.x == 1023) bsum[blockIdx.x] = sh[1023];
}

// merged scan2+scan3: each block wave-sums bsum[0..blockIdx) redundantly
__global__ __launch_bounds__(1024) void csr_scan23(int* __restrict__ rowptr,
                                                   const int* __restrict__ bsum,
                                                   int nb) {
    __shared__ int off_sh;
    int tid = threadIdx.x;
    if (tid < 64) {
        int v = (tid < blockIdx.x && tid < nb) ? bsum[tid] : 0;
        for (int off = 32; off > 0; off >>= 1) v += __shfl_down(v, off);
        if (tid == 0) off_sh = v;
    }
    __syncthreads();
    int i = blockIdx.x * 1024 + tid;
    if (i < NN) rowptr[i] += off_sh;
    if (i == 0) rowptr[NN] = NE;
}

__global__ void csr_fill(const int* __restrict__ ei, const void* __restrict__ edge_attr,
                         const int* __restrict__ rowptr, const int* __restrict__ pos,
                         float4* __restrict__ edata, const int* __restrict__ flags) {
    int e = blockIdx.x * 256 + threadIdx.x;
    if (e >= NE) return;
    int f64 = flags[0], isbf = flags[1];
    int s = ld_src(ei, e, f64), d = ld_dst(ei, e, f64);
    float4 ed;
    ed.x = ldx(edge_attr, (size_t)e * 3 + 0, isbf);
    ed.y = ldx(edge_attr, (size_t)e * 3 + 1, isbf);
    ed.z = ldx(edge_attr, (size_t)e * 3 + 2, isbf);
    ed.w = __int_as_float(s);
    edata[rowptr[d] + pos[e]] = ed;
}

// ---------------- per-layer kernels ----------------

// MFMA GEMM, wext fragments register-resident (r10-proven).
// xb layout (round-0): xb[node*256 + c*4 + k] = wcol k*64+c (head k, chan c).
__global__ __launch_bounds__(256) void node_linear(
    const void* __restrict__ h_in, const ushort_t* __restrict__ hbf,
    const ushort_t* __restrict__ zbuf, const ushort_t* __restrict__ wext,
    ushort_t* __restrict__ xb, float* __restrict__ a_src, float* __restrict__ a_dst,
    const int* __restrict__ flags, int layer) {
    __shared__ __align__(16) ushort_t st_all[4 * 16 * SROW];  // 33792 B
    int isbf = flags[1];
    int tid = threadIdx.x, wv = tid >> 6, lane = tid & 63;
    int q = lane >> 4, mi = lane & 15;
    const ushort_t* zsrc = (layer == 0) ? (isbf ? (const ushort_t*)h_in : hbf) : zbuf;
    const ushort_t* wl = wext + (size_t)layer * 272 * 64;
    bf16x8 wf[34];
#pragma unroll
    for (int t = 0; t < 17; ++t) {
        const ushort_t* wrow = wl + (size_t)(t * 16 + mi) * 64;
        wf[2 * t]     = *(const bf16x8*)(wrow + q * 8);
        wf[2 * t + 1] = *(const bf16x8*)(wrow + 32 + q * 8);
    }
    ushort_t* st = st_all + wv * 16 * SROW;
    int gwave = blockIdx.x * 4 + wv, nwaves = gridDim.x * 4;
    for (int tile = gwave; tile < NN / 16; tile += nwaves) {
        int mbase = tile * 16, mynode = mbase + mi;
        const ushort_t* zrow = zsrc + (size_t)mynode * 64;
        bf16x8 b0 = *(const bf16x8*)(zrow + q * 8);
        bf16x8 b1 = *(const bf16x8*)(zrow + 32 + q * 8);
#pragma unroll
        for (int t = 0; t < 17; ++t) {
            f32x4 acc = {0.f, 0.f, 0.f, 0.f};
            // D col=lane&15 -> node, row=q*4+r -> wcol (verified r6/r7)
            acc = __builtin_amdgcn_mfma_f32_16x16x32_bf16(wf[2 * t], b0, acc, 0, 0, 0);
            acc = __builtin_amdgcn_mfma_f32_16x16x32_bf16(wf[2 * t + 1], b1, acc, 0, 0, 0);
            if (t < 16) {
                ushort4 pk;
                pk.x = f2bf(acc[0]);
                pk.y = f2bf(acc[1]);
                pk.z = f2bf(acc[2]);
                pk.w = f2bf(acc[3]);
                *(ushort4*)(st + mi * SROW + t * 16 + q * 4) = pk;
            } else {
                float4 av;
                av.x = acc[0]; av.y = acc[1]; av.z = acc[2]; av.w = acc[3];
                if (q == 0) *(float4*)(a_src + (size_t)mynode * 4) = av;
                else if (q == 1) *(float4*)(a_dst + (size_t)mynode * 4) = av;
            }
        }
        for (int nn = 0; nn < 16; ++nn) {
            int node = mbase + nn;
            ushort4 pk;
            pk.x = st[nn * SROW + lane];
            pk.y = st[nn * SROW + 64 + lane];
            pk.z = st[nn * SROW + 128 + lane];
            pk.w = st[nn * SROW + 192 + lane];
            *(ushort4*)(xb + (size_t)node * 256 + lane * 4) = pk;
        }
    }
}

// One wave per node. Lane owns one channel, all 4 heads.
// vs r0: zero-padded LDS (no tail conditionals in hot loop), denominators
// accumulated per-lane in phase 1 and reduced ONCE per node (not per chunk),
// gather loop 8-deep (2x MLP of r0) with pre-shifted byte offsets.
__global__ __launch_bounds__(256) void node_aggregate(
    const int* __restrict__ rowptr, const float4* __restrict__ edata,
    const float* __restrict__ a_src, const float* __restrict__ a_dst,
    const ushort_t* __restrict__ xb, const float* __restrict__ Mbuf,
    const void* __restrict__ bias, const void* __restrict__ gamma,
    const void* __restrict__ beta, ushort_t* __restrict__ zout,
    void* __restrict__ outp, const int* __restrict__ flags, int layer, int last) {
    __shared__ float4 wsh[4][64];
    __shared__ uint_t ssh[4][64];
    int isbf = flags[1];
    int wv = threadIdx.x >> 6;
    int lane = threadIdx.x & 63;
    int n = blockIdx.x * 4 + wv;
    float M[12];
#pragma unroll
    for (int i = 0; i < 12; ++i) M[i] = Mbuf[layer * 12 + i];
    float4 ad = *(const float4*)(a_dst + (size_t)n * 4);
    int start = rowptr[n], end = rowptr[n + 1];
    const char* xbl = (const char*)xb + lane * 8;  // lane's 8B within each row
    float acc0 = 0.f, acc1 = 0.f, acc2 = 0.f, acc3 = 0.f;
    float pd0 = 0.f, pd1 = 0.f, pd2 = 0.f, pd3 = 0.f;  // per-lane den partials
    for (int cb = start; cb < end; cb += 64) {
        int m = end - cb;
        if (m > 64) m = 64;
        float4 ex = make_float4(0.f, 0.f, 0.f, 0.f);
        uint_t so = 0;
        if (lane < m) {
            float4 ed = edata[cb + lane];
            int s = __float_as_int(ed.w);
            so = (uint_t)s << 9;  // row byte offset (512 B/row)
            float4 as4 = *(const float4*)(a_src + (size_t)s * 4);
            float t0 = as4.x + ad.x + ed.x * M[0] + ed.y * M[1] + ed.z * M[2];
            float t1 = as4.y + ad.y + ed.x * M[3] + ed.y * M[4] + ed.z * M[5];
            float t2 = as4.z + ad.z + ed.x * M[6] + ed.y * M[7] + ed.z * M[8];
            float t3 = as4.w + ad.w + ed.x * M[9] + ed.y * M[10] + ed.z * M[11];
            t0 = t0 > 0.f ? t0 : NEG_SLOPE * t0;
            t1 = t1 > 0.f ? t1 : NEG_SLOPE * t1;
            t2 = t2 > 0.f ? t2 : NEG_SLOPE * t2;
            t3 = t3 > 0.f ? t3 : NEG_SLOPE * t3;
            ex.x = __expf(fminf(t0, 80.f));
            ex.y = __expf(fminf(t1, 80.f));
            ex.z = __expf(fminf(t2, 80.f));
            ex.w = __expf(fminf(t3, 80.f));
        }
        wsh[wv][lane] = ex;   // lanes >= m write zeros: no tail in gather loop
        ssh[wv][lane] = so;   // padded slots gather (cached) row 0 with w=0
        pd0 += ex.x; pd1 += ex.y; pd2 += ex.z; pd3 += ex.w;
        int m8 = (m + 7) & ~7;
        for (int j = 0; j < m8; j += 8) {
            uint_t off[8];
            ushort4 xv[8];
            float4 w4[8];
#pragma unroll
            for (int i = 0; i < 8; ++i) off[i] = ssh[wv][j + i];
#pragma unroll
            for (int i = 0; i < 8; ++i)
                xv[i] = *(const ushort4*)(xbl + off[i]);
#pragma unroll
            for (int i = 0; i < 8; ++i) w4[i] = wsh[wv][j + i];
#pragma unroll
            for (int i = 0; i < 8; ++i) {
                acc0 = fmaf(w4[i].x, bf2f(xv[i].x), acc0);
                acc1 = fmaf(w4[i].y, bf2f(xv[i].y), acc1);
                acc2 = fmaf(w4[i].z, bf2f(xv[i].z), acc2);
                acc3 = fmaf(w4[i].w, bf2f(xv[i].w), acc3);
            }
        }
    }
    // denominators: one wave-reduction per node
    for (int off = 1; off < 64; off <<= 1) {
        pd0 += __shfl_xor(pd0, off);
        pd1 += __shfl_xor(pd1, off);
        pd2 += __shfl_xor(pd2, off);
        pd3 += __shfl_xor(pd3, off);
    }
    float v = ldx(bias, layer * 64 + lane, isbf) +
              0.25f * (acc0 / (pd0 + 1e-16f) + acc1 / (pd1 + 1e-16f) +
                       acc2 / (pd2 + 1e-16f) + acc3 / (pd3 + 1e-16f));
    float sum = v;
    for (int off = 1; off < 64; off <<= 1) sum += __shfl_xor(sum, off);
    float mu = sum * (1.f / 64.f);
    float d = v - mu;
    float vv = d * d;
    for (int off = 1; off < 64; off <<= 1) vv += __shfl_xor(vv, off);
    float var = vv * (1.f / 64.f);
    float ln = d * rsqrtf(var + LN_EPS) * ldx(gamma, layer * 64 + lane, isbf) +
               ldx(beta, layer * 64 + lane, isbf);
    float sl = ln / (1.f + __expf(-ln));
    size_t idx = (size_t)n * 64 + lane;
    if (last) {
        if (isbf) ((ushort_t*)outp)[idx] = f2bf(sl);
        else      ((float*)outp)[idx] = sl;
    } else {
        zout[idx] = f2bf(sl);
    }
}

extern "C" void kernel_launch(void* const* d_in, const int* in_sizes, int n_in,
                              void* d_out, int out_size, void* d_ws, size_t ws_size,
                              hipStream_t stream) {
    int off = (in_sizes[0] == 1) ? 1 : 0;
    const void* h_in  = d_in[off + 0];
    const int*  ei    = (const int*)d_in[off + 1];
    const void* eattr = d_in[off + 2];
    const void* linW  = d_in[off + 3];
    const void* linEW = d_in[off + 4];
    const void* attS  = d_in[off + 5];
    const void* attD  = d_in[off + 6];
    const void* attE  = d_in[off + 7];
    const void* bias  = d_in[off + 8];
    const void* gamma = d_in[off + 9];
    const void* beta  = d_in[off + 10];

    // bump allocator, 256 B aligned (~56.5 MB)
    char* w = (char*)d_ws;
    size_t o = 0;
    auto alloc = [&](size_t bytes) {
        void* q = w + o;
        o += (bytes + 255) & ~(size_t)255;
        return q;
    };
    int*    flags  = (int*)alloc(8);
    float*  Mbuf   = (float*)alloc(24 * 4);
    ushort_t* wext = (ushort_t*)alloc((size_t)2 * 272 * 64 * 2);
    float*  a_src  = (float*)alloc((size_t)NN * 4 * 4);
    float*  a_dst  = (float*)alloc((size_t)NN * 4 * 4);
    int*    rowptr = (int*)alloc((size_t)(NN + 1) * 4);
    int*    deg    = (int*)alloc((size_t)NN * 4);
    int*    pos    = (int*)alloc((size_t)NE * 4);
    int*    bsum   = (int*)alloc(256 * 4);
    ushort_t* zbuf = (ushort_t*)alloc((size_t)NN * 64 * 2);
    ushort_t* hbf  = (ushort_t*)alloc((size_t)NN * 64 * 2);
    ushort_t* xb   = (ushort_t*)alloc((size_t)NN * 256 * 2);
    float4* edata  = (float4*)alloc((size_t)NE * 16);

    int nb = (NN + 1023) / 1024;  // 49
    setup<<<256, 256, 0, stream>>>(linW, linEW, attS, attD, attE, h_in, ei,
                                   Mbuf, wext, hbf, deg, flags);
    csr_hist_pos<<<(NE + 255) / 256, 256, 0, stream>>>(ei, deg, pos, flags);
    csr_scan1<<<nb, 1024, 0, stream>>>(deg, rowptr, bsum);
    csr_scan23<<<nb, 1024, 0, stream>>>(rowptr, bsum, nb);
    csr_fill<<<(NE + 255) / 256, 256, 0, stream>>>(ei, eattr, rowptr, pos, edata, flags);

    for (int l = 0; l < 2; ++l) {
        node_linear<<<512, 256, 0, stream>>>(h_in, hbf, zbuf, wext, xb,
                                             a_src, a_dst, flags, l);
        node_aggregate<<<NN / 4, 256, 0, stream>>>(rowptr, edata, a_src, a_dst,
                                                   xb, Mbuf, bias, gamma, beta,
                                                   zbuf, d_out, flags, l, l == 1);
    }
}

// Round 4
// 313.845 us; speedup vs baseline: 1.1317x; 1.0718x over previous
//
#include <hip/hip_runtime.h>
#include <math.h>

#define NN 50000
#define NE 800000
#define NEG_SLOPE 0.2f
#define LN_EPS 1e-5f
#define SROW 264  // LDS stage row stride in ushorts (256 + 8 pad)

typedef unsigned short ushort_t;
typedef unsigned int uint_t;
typedef __attribute__((ext_vector_type(8))) short bf16x8;
typedef __attribute__((ext_vector_type(4))) float f32x4;

__device__ __forceinline__ float bf2f(ushort_t u) {
    return __uint_as_float(((uint_t)u) << 16);
}
__device__ __forceinline__ ushort_t f2bf(float f) {
    uint_t b = __float_as_uint(f);
    uint_t r = (b + 0x7fffu + ((b >> 16) & 1u)) >> 16;
    return (ushort_t)r;
}
__device__ __forceinline__ float ldx(const void* p, size_t i, int isbf) {
    return isbf ? bf2f(((const ushort_t*)p)[i]) : ((const float*)p)[i];
}
__device__ __forceinline__ int clampN(int v) {
    return v < 0 ? 0 : (v >= NN ? NN - 1 : v);
}
__device__ __forceinline__ int sniff_f64(const int* ei) {
    return (ei[1] == 0 && ei[3] == 0 && ei[5] == 0 && ei[7] == 0) ? 1 : 0;
}

// Merged setup: flags + zero deg + M (block0) + W_ext + ei -> int32 esrc/edst.
// (hbf pass removed: f32->bf16 conversion now inlined in node_linear's
// fragment load, which touches each z-row exactly once.)
__global__ __launch_bounds__(256) void setup(
    const void* __restrict__ lin_W, const void* __restrict__ lin_edge_W,
    const void* __restrict__ att_src, const void* __restrict__ att_dst,
    const void* __restrict__ att_edge, const void* __restrict__ h_in,
    const int* __restrict__ ei, float* __restrict__ Mbuf,
    ushort_t* __restrict__ wext, int* __restrict__ esrc, int* __restrict__ edst,
    int* __restrict__ deg, int* __restrict__ flags) {
    int tid = threadIdx.x, lane = tid & 63;
    int nthreads = gridDim.x * 256;
    int gtid = blockIdx.x * 256 + tid;
    // parallel bf16-sniff: 256 lanes check one even ushort each (was a
    // 256-iteration serial loop on lane 0 of every block)
    __shared__ int s_bf;
    if (tid == 0) s_bf = 1;
    __syncthreads();
    {
        uint_t ex = (((const ushort_t*)h_in)[2 * tid] >> 7) & 0xFFu;
        if (ex > 0x8Cu) s_bf = 0;  // |v| >= ~1e4 -> not bf16 data
    }
    __syncthreads();
    int isbf = s_bf;
    int f64 = sniff_f64(ei);
    if (gtid == 0) {
        flags[0] = f64;
        flags[1] = isbf;
    }
    for (int i = gtid; i < NN; i += nthreads) deg[i] = 0;
    // ei (int64 or int32) -> clamped int32 esrc/edst, decoded ONCE here
    // (hist+fill then read coalesced int32 instead of stride-8 int64 twice)
    if (f64) {
        const int4* s4 = (const int4*)ei;
        const int4* d4 = (const int4*)(ei + 2 * NE);
        for (int p = gtid; p < NE / 2; p += nthreads) {
            int4 sv = s4[p], dv = d4[p];
            esrc[2 * p]     = clampN(sv.x);
            esrc[2 * p + 1] = clampN(sv.z);
            edst[2 * p]     = clampN(dv.x);
            edst[2 * p + 1] = clampN(dv.z);
        }
    } else {
        const int2* s2 = (const int2*)ei;
        const int2* d2 = (const int2*)(ei + NE);
        for (int p = gtid; p < NE / 2; p += nthreads) {
            int2 sv = s2[p], dv = d2[p];
            esrc[2 * p]     = clampN(sv.x);
            esrc[2 * p + 1] = clampN(sv.y);
            edst[2 * p]     = clampN(dv.x);
            edst[2 * p + 1] = clampN(dv.y);
        }
    }
    if (blockIdx.x == 0) {
        for (int rep = 0; rep < 2; ++rep) {
            int idx = rep * 256 + tid;  // l=idx>>8, h=(idx>>6)&3, c=idx&63
            int l = idx >> 8, hc = idx & 255;
            float ae = ldx(att_edge, l * 256 + hc, isbf);
            size_t b3 = ((size_t)l * 256 + hc) * 3;
            float q0 = ae * ldx(lin_edge_W, b3 + 0, isbf);
            float q1 = ae * ldx(lin_edge_W, b3 + 1, isbf);
            float q2 = ae * ldx(lin_edge_W, b3 + 2, isbf);
            for (int off = 32; off > 0; off >>= 1) {
                q0 += __shfl_down(q0, off);
                q1 += __shfl_down(q1, off);
                q2 += __shfl_down(q2, off);
            }
            if (lane == 0) {
                int h = (idx >> 6) & 3;
                Mbuf[(l * 4 + h) * 3 + 0] = q0;
                Mbuf[(l * 4 + h) * 3 + 1] = q1;
                Mbuf[(l * 4 + h) * 3 + 2] = q2;
            }
        }
    }
    // W_ext[l][272][64]: rows 0..255 = lin_W; 256..259 = u_src[h];
    // 260..263 = u_dst[h]; 264..271 = 0
    for (int idx = gtid; idx < 2 * 272 * 64; idx += nthreads) {
        int d = idx & 63;
        int row = (idx >> 6) % 272;
        int l = idx / (272 * 64);
        float v = 0.f;
        if (row < 256) {
            v = ldx(lin_W, ((size_t)l * 256 + row) * 64 + d, isbf);
        } else if (row < 264) {
            int h = (row - 256) & 3;
            const void* att = (row < 260) ? att_src : att_dst;
            for (int c = 0; c < 64; ++c) {
                v += ldx(lin_W, ((size_t)l * 256 + h * 64 + c) * 64 + d, isbf) *
                     ldx(att, l * 256 + h * 64 + c, isbf);
            }
        }
        wext[((size_t)l * 272 + row) * 64 + d] = f2bf(v);
    }
}

// ---------------- CSR build ----------------

__global__ void csr_hist_pos(const int* __restrict__ edst, int* __restrict__ deg,
                             int* __restrict__ pos) {
    int e = blockIdx.x * 256 + threadIdx.x;
    if (e >= NE) return;
    pos[e] = atomicAdd(&deg[edst[e]], 1);
}

__global__ __launch_bounds__(1024) void csr_scan1(const int* __restrict__ deg,
                                                  int* __restrict__ rowptr,
                                                  int* __restrict__ bsum) {
    __shared__ int sh[1024];
    int i = blockIdx.x * 1024 + threadIdx.x;
    int v = (i < NN) ? deg[i] : 0;
    sh[threadIdx.x] = v;
    __syncthreads();
    for (int off = 1; off < 1024; off <<= 1) {
        int t = (threadIdx.x >= off) ? sh[threadIdx.x - off] : 0;
        __syncthreads();
        sh[threadIdx.x] += t;
        __syncthreads();
    }
    if (i < NN) rowptr[i] = sh[threadIdx.x] - v;
    if (threadIdx.x == 1023) bsum[blockIdx.x] = sh[1023];
}

// merged scan2+scan3: each block wave-sums bsum[0..blockIdx) redundantly
__global__ __launch_bounds__(1024) void csr_scan23(int* __restrict__ rowptr,
                                                   const int* __restrict__ bsum,
                                                   int nb) {
    __shared__ int off_sh;
    int tid = threadIdx.x;
    if (tid < 64) {
        int v = (tid < blockIdx.x && tid < nb) ? bsum[tid] : 0;
        for (int off = 32; off > 0; off >>= 1) v += __shfl_down(v, off);
        if (tid == 0) off_sh = v;
    }
    __syncthreads();
    int i = blockIdx.x * 1024 + tid;
    if (i < NN) rowptr[i] += off_sh;
    if (i == 0) rowptr[NN] = NE;
}

__global__ void csr_fill(const int* __restrict__ esrc, const int* __restrict__ edst,
                         const void* __restrict__ edge_attr,
                         const int* __restrict__ rowptr, const int* __restrict__ pos,
                         float4* __restrict__ edata, const int* __restrict__ flags) {
    int e = blockIdx.x * 256 + threadIdx.x;
    if (e >= NE) return;
    int isbf = flags[1];
    int s = esrc[e], d = edst[e];
    float4 ed;
    ed.x = ldx(edge_attr, (size_t)e * 3 + 0, isbf);
    ed.y = ldx(edge_attr, (size_t)e * 3 + 1, isbf);
    ed.z = ldx(edge_attr, (size_t)e * 3 + 2, isbf);
    ed.w = __int_as_float(s);
    edata[rowptr[d] + pos[e]] = ed;
}

// ---------------- per-layer kernels ----------------

// MFMA GEMM, wext fragments register-resident (r10-proven).
// xb layout (round-0): xb[node*256 + c*4 + k] = wcol k*64+c (head k, chan c).
// f32 input converted to bf16 fragments inline (each z-row read exactly once).
__global__ __launch_bounds__(256) void node_linear(
    const void* __restrict__ h_in, const ushort_t* __restrict__ zbuf,
    const ushort_t* __restrict__ wext,
    ushort_t* __restrict__ xb, float* __restrict__ a_src, float* __restrict__ a_dst,
    const int* __restrict__ flags, int layer) {
    __shared__ __align__(16) ushort_t st_all[4 * 16 * SROW];  // 33792 B
    int isbf = flags[1];
    int tid = threadIdx.x, wv = tid >> 6, lane = tid & 63;
    int q = lane >> 4, mi = lane & 15;
    int f32path = (layer == 0) && !isbf;
    const ushort_t* zsrc = (layer == 0) ? (const ushort_t*)h_in : zbuf;
    const ushort_t* wl = wext + (size_t)layer * 272 * 64;
    bf16x8 wf[34];
#pragma unroll
    for (int t = 0; t < 17; ++t) {
        const ushort_t* wrow = wl + (size_t)(t * 16 + mi) * 64;
        wf[2 * t]     = *(const bf16x8*)(wrow + q * 8);
        wf[2 * t + 1] = *(const bf16x8*)(wrow + 32 + q * 8);
    }
    ushort_t* st = st_all + wv * 16 * SROW;
    int gwave = blockIdx.x * 4 + wv, nwaves = gridDim.x * 4;
    for (int tile = gwave; tile < NN / 16; tile += nwaves) {
        int mbase = tile * 16, mynode = mbase + mi;
        bf16x8 b0, b1;
        if (f32path) {
            const float* zf = (const float*)h_in + (size_t)mynode * 64;
            float4 fa = *(const float4*)(zf + q * 8);
            float4 fb = *(const float4*)(zf + q * 8 + 4);
            float4 fc = *(const float4*)(zf + 32 + q * 8);
            float4 fd = *(const float4*)(zf + 32 + q * 8 + 4);
            b0[0] = (short)f2bf(fa.x); b0[1] = (short)f2bf(fa.y);
            b0[2] = (short)f2bf(fa.z); b0[3] = (short)f2bf(fa.w);
            b0[4] = (short)f2bf(fb.x); b0[5] = (short)f2bf(fb.y);
            b0[6] = (short)f2bf(fb.z); b0[7] = (short)f2bf(fb.w);
            b1[0] = (short)f2bf(fc.x); b1[1] = (short)f2bf(fc.y);
            b1[2] = (short)f2bf(fc.z); b1[3] = (short)f2bf(fc.w);
            b1[4] = (short)f2bf(fd.x); b1[5] = (short)f2bf(fd.y);
            b1[6] = (short)f2bf(fd.z); b1[7] = (short)f2bf(fd.w);
        } else {
            const ushort_t* zrow = zsrc + (size_t)mynode * 64;
            b0 = *(const bf16x8*)(zrow + q * 8);
            b1 = *(const bf16x8*)(zrow + 32 + q * 8);
        }
#pragma unroll
        for (int t = 0; t < 17; ++t) {
            f32x4 acc = {0.f, 0.f, 0.f, 0.f};
            // D col=lane&15 -> node, row=q*4+r -> wcol (verified r6/r7)
            acc = __builtin_amdgcn_mfma_f32_16x16x32_bf16(wf[2 * t], b0, acc, 0, 0, 0);
            acc = __builtin_amdgcn_mfma_f32_16x16x32_bf16(wf[2 * t + 1], b1, acc, 0, 0, 0);
            if (t < 16) {
                ushort4 pk;
                pk.x = f2bf(acc[0]);
                pk.y = f2bf(acc[1]);
                pk.z = f2bf(acc[2]);
                pk.w = f2bf(acc[3]);
                *(ushort4*)(st + mi * SROW + t * 16 + q * 4) = pk;
            } else {
                float4 av;
                av.x = acc[0]; av.y = acc[1]; av.z = acc[2]; av.w = acc[3];
                if (q == 0) *(float4*)(a_src + (size_t)mynode * 4) = av;
                else if (q == 1) *(float4*)(a_dst + (size_t)mynode * 4) = av;
            }
        }
        for (int nn = 0; nn < 16; ++nn) {
            int node = mbase + nn;
            ushort4 pk;
            pk.x = st[nn * SROW + lane];
            pk.y = st[nn * SROW + 64 + lane];
            pk.z = st[nn * SROW + 128 + lane];
            pk.w = st[nn * SROW + 192 + lane];
            *(ushort4*)(xb + (size_t)node * 256 + lane * 4) = pk;
        }
    }
}

// One wave per node; gather loop 4-deep pipelined with SCALAR registers only
// (clamped index + zeroed weight for the tail -- no dynamic private arrays,
// no scratch spill). Verbatim round-0 version: proven 62 us, at the
// ~205 MB / ~3.45 TB/s beyond-L2 fabric roofline (FETCH = 8 XCDs x xb).
__global__ __launch_bounds__(256) void node_aggregate(
    const int* __restrict__ rowptr, const float4* __restrict__ edata,
    const float* __restrict__ a_src, const float* __restrict__ a_dst,
    const ushort_t* __restrict__ xb, const float* __restrict__ Mbuf,
    const void* __restrict__ bias, const void* __restrict__ gamma,
    const void* __restrict__ beta, ushort_t* __restrict__ zout,
    void* __restrict__ outp, const int* __restrict__ flags, int layer, int last) {
    __shared__ float4 wsh[4][64];
    __shared__ int ssh[4][64];
    int isbf = flags[1];
    int wv = threadIdx.x >> 6;
    int lane = threadIdx.x & 63;
    int n = blockIdx.x * 4 + wv;
    float M[12];
#pragma unroll
    for (int i = 0; i < 12; ++i) M[i] = Mbuf[layer * 12 + i];
    float4 ad = *(const float4*)(a_dst + (size_t)n * 4);
    int start = rowptr[n], end = rowptr[n + 1];
    float acc0 = 0.f, acc1 = 0.f, acc2 = 0.f, acc3 = 0.f;
    float den0 = 0.f, den1 = 0.f, den2 = 0.f, den3 = 0.f;
    for (int cb = start; cb < end; cb += 64) {
        int m = end - cb;
        if (m > 64) m = 64;
        if (lane < m) {
            float4 ed = edata[cb + lane];
            int s = __float_as_int(ed.w);
            float4 as4 = *(const float4*)(a_src + (size_t)s * 4);
            float t0 = as4.x + ad.x + ed.x * M[0] + ed.y * M[1] + ed.z * M[2];
            float t1 = as4.y + ad.y + ed.x * M[3] + ed.y * M[4] + ed.z * M[5];
            float t2 = as4.z + ad.z + ed.x * M[6] + ed.y * M[7] + ed.z * M[8];
            float t3 = as4.w + ad.w + ed.x * M[9] + ed.y * M[10] + ed.z * M[11];
            t0 = t0 > 0.f ? t0 : NEG_SLOPE * t0;
            t1 = t1 > 0.f ? t1 : NEG_SLOPE * t1;
            t2 = t2 > 0.f ? t2 : NEG_SLOPE * t2;
            t3 = t3 > 0.f ? t3 : NEG_SLOPE * t3;
            float4 ex;
            ex.x = __expf(fminf(t0, 80.f));
            ex.y = __expf(fminf(t1, 80.f));
            ex.z = __expf(fminf(t2, 80.f));
            ex.w = __expf(fminf(t3, 80.f));
            wsh[wv][lane] = ex;
            ssh[wv][lane] = s;
        }
        for (int j = 0; j < m; j += 4) {
            // clamped indices; invalid slots get zero weight (scalars only)
            int j1 = j + 1 < m ? j + 1 : m - 1;
            int j2 = j + 2 < m ? j + 2 : m - 1;
            int j3 = j + 3 < m ? j + 3 : m - 1;
            int s0 = ssh[wv][j],  s1 = ssh[wv][j1];
            int s2 = ssh[wv][j2], s3 = ssh[wv][j3];
            float4 w0 = wsh[wv][j];
            float4 w1 = wsh[wv][j1];
            float4 w2 = wsh[wv][j2];
            float4 w3 = wsh[wv][j3];
            if (j + 1 >= m) w1 = make_float4(0.f, 0.f, 0.f, 0.f);
            if (j + 2 >= m) w2 = make_float4(0.f, 0.f, 0.f, 0.f);
            if (j + 3 >= m) w3 = make_float4(0.f, 0.f, 0.f, 0.f);
            ushort4 x0 = *(const ushort4*)(xb + (size_t)s0 * 256 + lane * 4);
            ushort4 x1 = *(const ushort4*)(xb + (size_t)s1 * 256 + lane * 4);
            ushort4 x2 = *(const ushort4*)(xb + (size_t)s2 * 256 + lane * 4);
            ushort4 x3 = *(const ushort4*)(xb + (size_t)s3 * 256 + lane * 4);
            acc0 += w0.x * bf2f(x0.x) + w1.x * bf2f(x1.x) +
                    w2.x * bf2f(x2.x) + w3.x * bf2f(x3.x);
            acc1 += w0.y * bf2f(x0.y) + w1.y * bf2f(x1.y) +
                    w2.y * bf2f(x2.y) + w3.y * bf2f(x3.y);
            acc2 += w0.z * bf2f(x0.z) + w1.z * bf2f(x1.z) +
                    w2.z * bf2f(x2.z) + w3.z * bf2f(x3.z);
            acc3 += w0.w * bf2f(x0.w) + w1.w * bf2f(x1.w) +
                    w2.w * bf2f(x2.w) + w3.w * bf2f(x3.w);
            den0 += w0.x + w1.x + w2.x + w3.x;
            den1 += w0.y + w1.y + w2.y + w3.y;
            den2 += w0.z + w1.z + w2.z + w3.z;
            den3 += w0.w + w1.w + w2.w + w3.w;
        }
    }
    float v = ldx(bias, layer * 64 + lane, isbf) +
              0.25f * (acc0 / (den0 + 1e-16f) + acc1 / (den1 + 1e-16f) +
                       acc2 / (den2 + 1e-16f) + acc3 / (den3 + 1e-16f));
    float sum = v;
    for (int off = 1; off < 64; off <<= 1) sum += __shfl_xor(sum, off);
    float mu = sum * (1.f / 64.f);
    float d = v - mu;
    float vv = d * d;
    for (int off = 1; off < 64; off <<= 1) vv += __shfl_xor(vv, off);
    float var = vv * (1.f / 64.f);
    float ln = d * rsqrtf(var + LN_EPS) * ldx(gamma, layer * 64 + lane, isbf) +
               ldx(beta, layer * 64 + lane, isbf);
    float sl = ln / (1.f + __expf(-ln));
    size_t idx = (size_t)n * 64 + lane;
    if (last) {
        if (isbf) ((ushort_t*)outp)[idx] = f2bf(sl);
        else      ((float*)outp)[idx] = sl;
    } else {
        zout[idx] = f2bf(sl);
    }
}

extern "C" void kernel_launch(void* const* d_in, const int* in_sizes, int n_in,
                              void* d_out, int out_size, void* d_ws, size_t ws_size,
                              hipStream_t stream) {
    int off = (in_sizes[0] == 1) ? 1 : 0;
    const void* h_in  = d_in[off + 0];
    const int*  ei    = (const int*)d_in[off + 1];
    const void* eattr = d_in[off + 2];
    const void* linW  = d_in[off + 3];
    const void* linEW = d_in[off + 4];
    const void* attS  = d_in[off + 5];
    const void* attD  = d_in[off + 6];
    const void* attE  = d_in[off + 7];
    const void* bias  = d_in[off + 8];
    const void* gamma = d_in[off + 9];
    const void* beta  = d_in[off + 10];

    // bump allocator, 256 B aligned (~56.5 MB)
    char* w = (char*)d_ws;
    size_t o = 0;
    auto alloc = [&](size_t bytes) {
        void* q = w + o;
        o += (bytes + 255) & ~(size_t)255;
        return q;
    };
    int*    flags  = (int*)alloc(8);
    float*  Mbuf   = (float*)alloc(24 * 4);
    ushort_t* wext = (ushort_t*)alloc((size_t)2 * 272 * 64 * 2);
    float*  a_src  = (float*)alloc((size_t)NN * 4 * 4);
    float*  a_dst  = (float*)alloc((size_t)NN * 4 * 4);
    int*    rowptr = (int*)alloc((size_t)(NN + 1) * 4);
    int*    deg    = (int*)alloc((size_t)NN * 4);
    int*    pos    = (int*)alloc((size_t)NE * 4);
    int*    bsum   = (int*)alloc(256 * 4);
    ushort_t* zbuf = (ushort_t*)alloc((size_t)NN * 64 * 2);
    int*    esrc   = (int*)alloc((size_t)NE * 4);
    int*    edst   = (int*)alloc((size_t)NE * 4);
    ushort_t* xb   = (ushort_t*)alloc((size_t)NN * 256 * 2);
    float4* edata  = (float4*)alloc((size_t)NE * 16);

    int nb = (NN + 1023) / 1024;  // 49
    setup<<<256, 256, 0, stream>>>(linW, linEW, attS, attD, attE, h_in, ei,
                                   Mbuf, wext, esrc, edst, deg, flags);
    csr_hist_pos<<<(NE + 255) / 256, 256, 0, stream>>>(edst, deg, pos);
    csr_scan1<<<nb, 1024, 0, stream>>>(deg, rowptr, bsum);
    csr_scan23<<<nb, 1024, 0, stream>>>(rowptr, bsum, nb);
    csr_fill<<<(NE + 255) / 256, 256, 0, stream>>>(esrc, edst, eattr, rowptr,
                                                   pos, edata, flags);

    for (int l = 0; l < 2; ++l) {
        node_linear<<<512, 256, 0, stream>>>(h_in, zbuf, wext, xb,
                                             a_src, a_dst, flags, l);
        node_aggregate<<<NN / 4, 256, 0, stream>>>(rowptr, edata, a_src, a_dst,
                                                   xb, Mbuf, bias, gamma, beta,
                                                   zbuf, d_out, flags, l, l == 1);
    }
}